// Round 1
// baseline (187.168 us; speedup 1.0000x reference)
//
#include <hip/hip_runtime.h>

#define LR 0.01f
#define NSTEPS 100

// One thread per batch row b (B = 1,048,576 rows, C = 4 outputs/row).
// u_{k+1} = u_k - LR*(2*q*u_k + p) == a*u_k + c with a = 1-2*LR*q, c = -LR*p.
// 4 independent FMA chains per thread (float4 components) hide the ~4-cycle
// dependent-FMA latency. Memory-bound: ~150 MB fetch (Q/p rows are 64 B,
// we need the last 16 B -> unavoidable ~4x sector over-fetch), ~17 MB write.
__global__ __launch_bounds__(256) void diffmpc_kernel(
    const float* __restrict__ Q,
    const float* __restrict__ p,
    const float* __restrict__ u0,
    float* __restrict__ out,
    int B)
{
    int b = blockIdx.x * blockDim.x + threadIdx.x;
    if (b >= B) return;

    // Q, p are (B, 16) row-major; cols 12..15 are the "u" part.
    // Byte offset b*64 + 48 is 16 B aligned -> single global_load_dwordx4.
    const float4 q4 = *reinterpret_cast<const float4*>(Q + (size_t)b * 16 + 12);
    const float4 p4 = *reinterpret_cast<const float4*>(p + (size_t)b * 16 + 12);
    float4 u = *reinterpret_cast<const float4*>(u0 + (size_t)b * 4);

    const float ax = fmaf(-2.0f * LR, q4.x, 1.0f);
    const float ay = fmaf(-2.0f * LR, q4.y, 1.0f);
    const float az = fmaf(-2.0f * LR, q4.z, 1.0f);
    const float aw = fmaf(-2.0f * LR, q4.w, 1.0f);
    const float cx = -LR * p4.x;
    const float cy = -LR * p4.y;
    const float cz = -LR * p4.z;
    const float cw = -LR * p4.w;

#pragma unroll 10
    for (int i = 0; i < NSTEPS; ++i) {
        u.x = fmaf(ax, u.x, cx);
        u.y = fmaf(ay, u.y, cy);
        u.z = fmaf(az, u.z, cz);
        u.w = fmaf(aw, u.w, cw);
    }

    *reinterpret_cast<float4*>(out + (size_t)b * 4) = u;
}

extern "C" void kernel_launch(void* const* d_in, const int* in_sizes, int n_in,
                              void* d_out, int out_size, void* d_ws, size_t ws_size,
                              hipStream_t stream) {
    // Inputs (setup_inputs order): x_init (B,12) [UNUSED], Q (B,16), p (B,16), u_init (B,4)
    const float* Q  = (const float*)d_in[1];
    const float* p  = (const float*)d_in[2];
    const float* u0 = (const float*)d_in[3];
    float* out = (float*)d_out;

    const int B = in_sizes[3] / 4;  // u_init has B*4 elements

    const int block = 256;
    const int grid = (B + block - 1) / block;
    diffmpc_kernel<<<grid, block, 0, stream>>>(Q, p, u0, out, B);
}